// Round 2
// baseline (895.181 us; speedup 1.0000x reference)
//
#include <hip/hip_runtime.h>
#include <hip/hip_bf16.h>
#include <math.h>

// ---------- types ----------
typedef short short8 __attribute__((ext_vector_type(8)));
typedef float f32x4 __attribute__((ext_vector_type(4)));

#define MFMA16(a, b, c) __builtin_amdgcn_mfma_f32_16x16x32_bf16((a), (b), (c), 0, 0, 0)

__device__ __forceinline__ unsigned short f2bf(float f) {
  unsigned u = __builtin_bit_cast(unsigned, f);
  u += 0x7FFFu + ((u >> 16) & 1u);   // RNE
  return (unsigned short)(u >> 16);
}

// ---------- small kernels ----------
__global__ __launch_bounds__(256) void cast_f32_bf16(const float* __restrict__ in,
                                                     unsigned short* __restrict__ out,
                                                     long n) {
  long i = ((long)blockIdx.x * 256 + threadIdx.x) * 4;
  if (i + 3 < n) {
    float4 v = *(const float4*)(in + i);
    ushort4 o;
    o.x = f2bf(v.x); o.y = f2bf(v.y); o.z = f2bf(v.z); o.w = f2bf(v.w);
    *(ushort4*)(out + i) = o;
  }
}

// W [K,N] fp32 -> Wt [N,K] bf16
__global__ __launch_bounds__(256) void wtrans(const float* __restrict__ w,
                                              unsigned short* __restrict__ wt,
                                              int K, int N) {
  int idx = blockIdx.x * 256 + threadIdx.x;
  if (idx < K * N) {
    int k = idx / N, n = idx - k * N;
    wt[(long)n * K + k] = f2bf(w[idx]);
  }
}

// pooled_raw[b,j,c] = mean_w x[b, j*5+w, c]  (bf16 out). block = one row (16*800 rows)
__global__ __launch_bounds__(256) void pool_mean(const float* __restrict__ x,
                                                 unsigned short* __restrict__ pr) {
  long bi = blockIdx.x;                 // 0..12799 == b*800 + j
  const float* src = x + bi * 2560;     // (b*4000 + j*5)*512
  int c = threadIdx.x * 2;
  float ax = 0.f, ay = 0.f;
#pragma unroll
  for (int w = 0; w < 5; ++w) {
    float2 v = *(const float2*)(src + w * 512 + c);
    ax += v.x; ay += v.y;
  }
  pr[bi * 512 + c]     = f2bf(ax * 0.2f);
  pr[bi * 512 + c + 1] = f2bf(ay * 0.2f);
}

// LayerNorm (eps 1e-5, biased var) + erf-GELU ; in fp32 [rows,512] -> out bf16
__global__ __launch_bounds__(256) void ln_gelu(const float* __restrict__ in,
                                               const float* __restrict__ g,
                                               const float* __restrict__ be,
                                               unsigned short* __restrict__ out) {
  long row = blockIdx.x;
  const float* src = in + row * 512;
  int tid = threadIdx.x;
  float2 v = *(const float2*)(src + tid * 2);
  float s = v.x + v.y, sq = v.x * v.x + v.y * v.y;
#pragma unroll
  for (int m = 1; m < 64; m <<= 1) {
    s  += __shfl_xor(s, m);
    sq += __shfl_xor(sq, m);
  }
  __shared__ float ss[4], ssq[4];
  int wv = tid >> 6;
  if ((tid & 63) == 0) { ss[wv] = s; ssq[wv] = sq; }
  __syncthreads();
  s  = ss[0] + ss[1] + ss[2] + ss[3];
  sq = ssq[0] + ssq[1] + ssq[2] + ssq[3];
  float mu = s * (1.0f / 512.0f);
  float var = sq * (1.0f / 512.0f) - mu * mu;
  float rs = rsqrtf(var + 1e-5f);
  int c = tid * 2;
#pragma unroll
  for (int e = 0; e < 2; ++e) {
    float xv = (e == 0 ? v.x : v.y);
    float y = (xv - mu) * rs * g[c + e] + be[c + e];
    float ge = 0.5f * y * (1.0f + erff(y * 0.70710678118654752f));
    out[row * 512 + c + e] = f2bf(ge);
  }
}

// ---------- GEMM: C[M,N] = A[M,K](bf16) @ Bt[N,K](bf16)^T + bias ----------
// 128x128 tile, BK=32, 4 waves (2x2), each wave 64x64 via 4x4 16x16x32 MFMA frags.
__global__ __launch_bounds__(256) void gemm_bf16(const unsigned short* __restrict__ A,
                                                 const unsigned short* __restrict__ Bt,
                                                 const float* __restrict__ bias,
                                                 void* __restrict__ Cout,
                                                 int M, int N, int K, int outFp32) {
  __shared__ unsigned short lA[128 * 32];
  __shared__ unsigned short lB[128 * 32];
  const int tid = threadIdx.x;
  const int lane = tid & 63, wv = tid >> 6;
  const int wr = wv >> 1, wc = wv & 1;
  const int l15 = lane & 15, lh8 = (lane >> 4) * 8;
  const int m0 = blockIdx.y * 128, n0 = blockIdx.x * 128;

  f32x4 acc[4][4] = {};

  for (int k0 = 0; k0 < K; k0 += 32) {
#pragma unroll
    for (int h = 0; h < 2; ++h) {
      int o = tid * 16 + h * 4096;        // byte offset in 8KB tile
      int r = o >> 6;                      // 64B per row (32 bf16)
      int cb = (o & 63) >> 1;              // element col
      *(float4*)((char*)lA + o) = *(const float4*)(A  + (size_t)(m0 + r) * K + k0 + cb);
      *(float4*)((char*)lB + o) = *(const float4*)(Bt + (size_t)(n0 + r) * K + k0 + cb);
    }
    __syncthreads();
    short8 af[4], bfr[4];
#pragma unroll
    for (int s2 = 0; s2 < 4; ++s2) {
      af[s2]  = *(const short8*)&lA[(wr * 64 + s2 * 16 + l15) * 32 + lh8];
      bfr[s2] = *(const short8*)&lB[(wc * 64 + s2 * 16 + l15) * 32 + lh8];
    }
#pragma unroll
    for (int i = 0; i < 4; ++i)
#pragma unroll
      for (int j = 0; j < 4; ++j)
        acc[i][j] = MFMA16(af[i], bfr[j], acc[i][j]);
    __syncthreads();
  }

#pragma unroll
  for (int i = 0; i < 4; ++i)
#pragma unroll
    for (int j = 0; j < 4; ++j) {
      int row0 = m0 + wr * 64 + i * 16 + (lane >> 4) * 4;
      int col  = n0 + wc * 64 + j * 16 + l15;
      float bb = bias[col];
#pragma unroll
      for (int r = 0; r < 4; ++r) {
        float vv = acc[i][j][r] + bb;
        size_t idx = (size_t)(row0 + r) * N + col;
        if (outFp32) ((float*)Cout)[idx] = vv;
        else ((unsigned short*)Cout)[idx] = f2bf(vv);
      }
    }
}

// ---------- generic flash attention ----------
// mode 0: grid attn. blockIdx.y -> (b,w,h) of 16*5*4 = 320; Q/K/V strided 5*768 in qkv.
// mode 1: pool attn. blockIdx.y -> (b,h) of 16*4; Q from qp, K/V from kvp.
// block: 256 thr (4 waves); Q tile 64 rows (16/wave); KV tile 32.
__global__ __launch_bounds__(256) void flash_attn(const unsigned short* __restrict__ qkv,
                                                  const unsigned short* __restrict__ qp,
                                                  const unsigned short* __restrict__ kvp,
                                                  unsigned short* __restrict__ cat,
                                                  int mode) {
  __shared__ unsigned short lK[32 * 64];   // [tok][d]
  __shared__ unsigned short lV[64 * 32];   // [d][tok] (transposed)
  __shared__ unsigned short lP[4][16 * 32];

  int bh = blockIdx.y, qt = blockIdx.x;
  const unsigned short *Qb, *Kb, *Vb;
  unsigned short* Ob;
  long qs, ks, os;
  int nq, nk;
  if (mode == 0) {
    int b = bh / 20, rem = bh % 20, w = rem >> 2, h = rem & 3;
    long base = ((long)b * 4000 + w) * 768;
    Qb = qkv + base + h * 64;
    Kb = qkv + base + 256 + h * 64;
    Vb = qkv + base + 512 + h * 64;
    qs = 5 * 768; ks = 5 * 768;
    Ob = cat + ((long)b * 4000 + w) * 512 + h * 64;
    os = 5 * 512;
    nq = 800; nk = 800;
  } else {
    int b = bh >> 2, h = bh & 3;
    Qb = qp + (long)b * 4000 * 256 + h * 64; qs = 256;
    Kb = kvp + (long)b * 800 * 512 + h * 64; ks = 512;
    Vb = Kb + 256;
    Ob = cat + (long)b * 4000 * 512 + 256 + h * 64; os = 512;
    nq = 4000; nk = 800;
  }

  int tid = threadIdx.x, lane = tid & 63, wv = tid >> 6;
  int l15 = lane & 15, lh8 = (lane >> 4) * 8;

  int qrow = qt * 64 + wv * 16 + l15;
  int qrc = qrow < nq ? qrow : nq - 1;
  short8 q0 = *(const short8*)(Qb + (long)qrc * qs + lh8);
  short8 q1 = *(const short8*)(Qb + (long)qrc * qs + 32 + lh8);

  float m[4]  = {-INFINITY, -INFINITY, -INFINITY, -INFINITY};
  float ls[4] = {0.f, 0.f, 0.f, 0.f};
  f32x4 oacc[4] = {};

  const int ntiles = nk >> 5;
  for (int t = 0; t < ntiles; ++t) {
    {   // stage K tile [32][64] linear: 256 thr x 16B
      int o = tid * 16;
      int tok = o >> 7, ce = (o & 127) >> 1;
      *(float4*)((char*)lK + o) = *(const float4*)(Kb + (long)(t * 32 + tok) * ks + ce);
    }
    {   // stage V^T: thread reads V[tok][dg..dg+7], scatters to lV[d][tok]
      int tok = tid >> 3, dg = (tid & 7) * 8;
      short8 v = *(const short8*)(Vb + (long)(t * 32 + tok) * ks + dg);
#pragma unroll
      for (int e = 0; e < 8; ++e) lV[(dg + e) * 32 + tok] = (unsigned short)v[e];
    }
    __syncthreads();

    // S = Q K^T  (2 col-subtiles of 16 tokens)
    f32x4 s[2];
#pragma unroll
    for (int ns = 0; ns < 2; ++ns) {
      short8 k0 = *(const short8*)&lK[(ns * 16 + l15) * 64 + lh8];
      short8 k1 = *(const short8*)&lK[(ns * 16 + l15) * 64 + 32 + lh8];
      f32x4 z = {};
      z = MFMA16(q0, k0, z);
      z = MFMA16(q1, k1, z);
      s[ns] = z;
    }

    // online softmax (rows = (lane>>4)*4 + r ; 16 lanes per row-group)
#pragma unroll
    for (int r = 0; r < 4; ++r) {
      float s0 = s[0][r] * 0.125f, s1 = s[1][r] * 0.125f;
      float pm = fmaxf(s0, s1);
      pm = fmaxf(pm, __shfl_xor(pm, 1));
      pm = fmaxf(pm, __shfl_xor(pm, 2));
      pm = fmaxf(pm, __shfl_xor(pm, 4));
      pm = fmaxf(pm, __shfl_xor(pm, 8));
      float mn = fmaxf(m[r], pm);
      float sc = __expf(m[r] - mn);
      float p0 = __expf(s0 - mn), p1 = __expf(s1 - mn);
      m[r] = mn;
      ls[r] = ls[r] * sc + p0 + p1;
#pragma unroll
      for (int n = 0; n < 4; ++n) oacc[n][r] *= sc;
      int prow = (lane >> 4) * 4 + r;
      lP[wv][prow * 32 + l15]      = f2bf(p0);
      lP[wv][prow * 32 + 16 + l15] = f2bf(p1);
    }
    __syncthreads();

    // O += P V
    short8 pf = *(const short8*)&lP[wv][l15 * 32 + lh8];
#pragma unroll
    for (int n = 0; n < 4; ++n) {
      short8 vf = *(const short8*)&lV[(n * 16 + l15) * 32 + lh8];
      oacc[n] = MFMA16(pf, vf, oacc[n]);
    }
    __syncthreads();
  }

  // finalize
#pragma unroll
  for (int r = 0; r < 4; ++r) {
    float sum = ls[r];
    sum += __shfl_xor(sum, 1);
    sum += __shfl_xor(sum, 2);
    sum += __shfl_xor(sum, 4);
    sum += __shfl_xor(sum, 8);
    float inv = 1.0f / sum;
    int row = qt * 64 + wv * 16 + (lane >> 4) * 4 + r;
    if (row < nq) {
#pragma unroll
      for (int n = 0; n < 4; ++n) {
        int col = n * 16 + l15;
        Ob[(long)row * os + col] = f2bf(oacc[n][r] * inv);
      }
    }
  }
}

// ---------- launch ----------
extern "C" void kernel_launch(void* const* d_in, const int* in_sizes, int n_in,
                              void* d_out, int out_size, void* d_ws, size_t ws_size,
                              hipStream_t stream) {
  const float* x      = (const float*)d_in[0];
  const float* gqkv_w = (const float*)d_in[1];
  const float* gqkv_b = (const float*)d_in[2];
  const float* pq_w   = (const float*)d_in[3];
  const float* pq_b   = (const float*)d_in[4];
  const float* pkv_w  = (const float*)d_in[5];
  const float* pkv_b  = (const float*)d_in[6];
  const float* conv_w = (const float*)d_in[7];
  const float* conv_b = (const float*)d_in[8];
  const float* ln_g   = (const float*)d_in[9];
  const float* ln_b   = (const float*)d_in[10];
  const float* proj_w = (const float*)d_in[11];
  const float* proj_b = (const float*)d_in[12];

  char* ws = (char*)d_ws;
  // layout (bytes); CAT aliases XBF (XBF dead after the qp GEMM, CAT written after)
  unsigned short* xbf  = (unsigned short*)(ws + 0);
  unsigned short* cat  = xbf;
  unsigned short* qkv  = (unsigned short*)(ws + 65536000);
  unsigned short* qp   = (unsigned short*)(ws + 163840000);
  unsigned short* pr   = (unsigned short*)(ws + 196608000);
  float*          cvt  = (float*)        (ws + 209715200);
  unsigned short* p2   = (unsigned short*)(ws + 235929600);
  unsigned short* kvp  = (unsigned short*)(ws + 249036800);
  unsigned short* wtg  = (unsigned short*)(ws + 262144000);
  unsigned short* wtq  = (unsigned short*)(ws + 262930432);
  unsigned short* wtkv = (unsigned short*)(ws + 263192576);
  unsigned short* wtc  = (unsigned short*)(ws + 263716864);
  unsigned short* wtp  = (unsigned short*)(ws + 264241152);

  // prep
  cast_f32_bf16<<<32000, 256, 0, stream>>>(x, xbf, 64000L * 512);
  wtrans<<<(512 * 768 + 255) / 256, 256, 0, stream>>>(gqkv_w, wtg, 512, 768);
  wtrans<<<(512 * 256 + 255) / 256, 256, 0, stream>>>(pq_w, wtq, 512, 256);
  wtrans<<<(512 * 512 + 255) / 256, 256, 0, stream>>>(pkv_w, wtkv, 512, 512);
  wtrans<<<(512 * 512 + 255) / 256, 256, 0, stream>>>(conv_w, wtc, 512, 512);
  wtrans<<<(512 * 512 + 255) / 256, 256, 0, stream>>>(proj_w, wtp, 512, 512);
  pool_mean<<<12800, 256, 0, stream>>>(x, pr);

  // projections
  gemm_bf16<<<dim3(6, 500), 256, 0, stream>>>(xbf, wtg, gqkv_b, qkv, 64000, 768, 512, 0);
  gemm_bf16<<<dim3(2, 500), 256, 0, stream>>>(xbf, wtq, pq_b, qp, 64000, 256, 512, 0);
  gemm_bf16<<<dim3(4, 100), 256, 0, stream>>>(pr, wtc, conv_b, cvt, 12800, 512, 512, 1);
  ln_gelu<<<12800, 256, 0, stream>>>(cvt, ln_g, ln_b, p2);
  gemm_bf16<<<dim3(4, 100), 256, 0, stream>>>(p2, wtkv, pkv_b, kvp, 12800, 512, 512, 0);

  // attentions -> cat   (grid: 16 b * 5 w * 4 h = 320 y-blocks — was 1280, OOB corruption)
  flash_attn<<<dim3(13, 320), 256, 0, stream>>>(qkv, qp, kvp, cat, 0);
  flash_attn<<<dim3(63, 64), 256, 0, stream>>>(qkv, qp, kvp, cat, 1);

  // output projection (fp32 out)
  gemm_bf16<<<dim3(4, 500), 256, 0, stream>>>(cat, wtp, proj_b, d_out, 64000, 512, 512, 1);
}

// Round 3
// 611.616 us; speedup vs baseline: 1.4636x; 1.4636x over previous
//
#include <hip/hip_runtime.h>
#include <hip/hip_bf16.h>
#include <math.h>

// ---------- types ----------
typedef short short8 __attribute__((ext_vector_type(8)));
typedef float f32x4 __attribute__((ext_vector_type(4)));

#define MFMA16(a, b, c) __builtin_amdgcn_mfma_f32_16x16x32_bf16((a), (b), (c), 0, 0, 0)
#define NEGBIG (-1e30f)

__device__ __forceinline__ unsigned short f2bf(float f) {
  unsigned u = __builtin_bit_cast(unsigned, f);
  u += 0x7FFFu + ((u >> 16) & 1u);   // RNE
  return (unsigned short)(u >> 16);
}
__device__ __forceinline__ float b2f(unsigned short h) {
  return __builtin_bit_cast(float, (unsigned)h << 16);
}
__device__ __forceinline__ unsigned cvtpk(float lo, float hi) {
  unsigned r;
  asm("v_cvt_pk_bf16_f32 %0, %1, %2" : "=v"(r) : "v"(lo), "v"(hi));
  return r;
}

// ---------- small kernels ----------
__global__ __launch_bounds__(256) void cast_f32_bf16(const float* __restrict__ in,
                                                     unsigned short* __restrict__ out,
                                                     long n) {
  long i = ((long)blockIdx.x * 256 + threadIdx.x) * 4;
  if (i + 3 < n) {
    float4 v = *(const float4*)(in + i);
    ushort4 o;
    o.x = f2bf(v.x); o.y = f2bf(v.y); o.z = f2bf(v.z); o.w = f2bf(v.w);
    *(ushort4*)(out + i) = o;
  }
}

// W [K,N] fp32 -> Wt [N,K] bf16
__global__ __launch_bounds__(256) void wtrans(const float* __restrict__ w,
                                              unsigned short* __restrict__ wt,
                                              int K, int N) {
  int idx = blockIdx.x * 256 + threadIdx.x;
  if (idx < K * N) {
    int k = idx / N, n = idx - k * N;
    wt[(long)n * K + k] = f2bf(w[idx]);
  }
}

// pooled[b,j,c] = mean_w xbf[b, j*5+w, c]  (bf16 in, bf16 out)
__global__ __launch_bounds__(256) void pool_mean(const unsigned short* __restrict__ x,
                                                 unsigned short* __restrict__ pr) {
  long bi = blockIdx.x;                 // b*800 + j
  const unsigned short* src = x + bi * 2560;
  int c = threadIdx.x * 2;
  float ax = 0.f, ay = 0.f;
#pragma unroll
  for (int w = 0; w < 5; ++w) {
    unsigned v = *(const unsigned*)(src + w * 512 + c);
    ax += b2f((unsigned short)(v & 0xffff));
    ay += b2f((unsigned short)(v >> 16));
  }
  unsigned out = (unsigned)f2bf(ax * 0.2f) | ((unsigned)f2bf(ay * 0.2f) << 16);
  *(unsigned*)(pr + bi * 512 + c) = out;
}

// LayerNorm (eps 1e-5, biased var) + erf-GELU ; fp32 [rows,512] -> bf16
__global__ __launch_bounds__(256) void ln_gelu(const float* __restrict__ in,
                                               const float* __restrict__ g,
                                               const float* __restrict__ be,
                                               unsigned short* __restrict__ out) {
  long row = blockIdx.x;
  const float* src = in + row * 512;
  int tid = threadIdx.x;
  float2 v = *(const float2*)(src + tid * 2);
  float s = v.x + v.y, sq = v.x * v.x + v.y * v.y;
#pragma unroll
  for (int m = 1; m < 64; m <<= 1) {
    s  += __shfl_xor(s, m);
    sq += __shfl_xor(sq, m);
  }
  __shared__ float ss[4], ssq[4];
  int wv = tid >> 6;
  if ((tid & 63) == 0) { ss[wv] = s; ssq[wv] = sq; }
  __syncthreads();
  s  = ss[0] + ss[1] + ss[2] + ss[3];
  sq = ssq[0] + ssq[1] + ssq[2] + ssq[3];
  float mu = s * (1.0f / 512.0f);
  float var = sq * (1.0f / 512.0f) - mu * mu;
  float rs = rsqrtf(var + 1e-5f);
  int c = tid * 2;
#pragma unroll
  for (int e = 0; e < 2; ++e) {
    float xv = (e == 0 ? v.x : v.y);
    float y = (xv - mu) * rs * g[c + e] + be[c + e];
    float ge = 0.5f * y * (1.0f + erff(y * 0.70710678118654752f));
    out[row * 512 + c + e] = f2bf(ge);
  }
}

// ---------- V transpose: src [seq][800+pad rows][64] -> dst [seq][64][800] ----------
__global__ __launch_bounds__(256) void vtrans(const unsigned short* __restrict__ src,
                                              unsigned short* __restrict__ dst) {
  __shared__ unsigned short tile[64][64];
  int jt = blockIdx.x, s = blockIdx.y;
  int tid = threadIdx.x;
#pragma unroll
  for (int p = 0; p < 2; ++p) {
    int idx = p * 256 + tid;            // j = idx>>3, d8 = (idx&7)*8
    int j = idx >> 3, d8 = (idx & 7) * 8;
    int jg = min(jt * 64 + j, 799);
    short8 v = *(const short8*)(src + ((long)s * 800 + jg) * 64 + d8);
    *(short8*)&tile[j][d8] = v;
  }
  __syncthreads();
  int d = tid >> 2, jseg = (tid & 3) * 16;
  if (jt * 64 + jseg < 800) {
    short8 h0, h1;
#pragma unroll
    for (int i = 0; i < 8; ++i) { h0[i] = (short)tile[jseg + i][d]; h1[i] = (short)tile[jseg + 8 + i][d]; }
    unsigned short* o = dst + ((long)s * 64 + d) * 800 + jt * 64 + jseg;
    *(short8*)o = h0;
    *(short8*)(o + 8) = h1;
  }
}

// ---------- GEMM: C[M,N] = A[M,K](bf16) @ Bt[N,K](bf16)^T + bias ----------
// 128x128 tile, BK=32, 4 waves (2x2). LDS XOR-swizzled (2-bit).
// gmode 0: bf16 out0 [M][N]; 1: fp32 out0 [M][N];
// gmode 2: qkv-split gathered: out0=Q[320][800][64], out1=K, out2=V (M=64000,N=768)
// gmode 3: kv-split gathered:  out0=K[64][800][64], out1=V (M=12800,N=512)
__global__ __launch_bounds__(256) void gemm_bf16(const unsigned short* __restrict__ A,
                                                 const unsigned short* __restrict__ Bt,
                                                 const float* __restrict__ bias,
                                                 void* __restrict__ out0, void* __restrict__ out1,
                                                 void* __restrict__ out2,
                                                 int M, int N, int K, int gmode) {
  __shared__ unsigned short lA[128 * 32];
  __shared__ unsigned short lB[128 * 32];
  const int tid = threadIdx.x;
  const int lane = tid & 63, wv = tid >> 6;
  const int wr = wv >> 1, wc = wv & 1;
  const int l15 = lane & 15, lg = lane >> 4;
  const int m0 = blockIdx.y * 128, n0 = blockIdx.x * 128;

  f32x4 acc[4][4] = {};

  for (int k0 = 0; k0 < K; k0 += 32) {
#pragma unroll
    for (int h = 0; h < 2; ++h) {
      int o = tid * 16 + h * 4096;
      int r = o >> 6;                    // 64B per row (32 bf16)
      int cb = o & 63;
      int so = (o & ~63) | (cb ^ ((r & 3) << 4));
      *(float4*)((char*)lA + so) = *(const float4*)(A  + (size_t)(m0 + r) * K + k0 + (cb >> 1));
      *(float4*)((char*)lB + so) = *(const float4*)(Bt + (size_t)(n0 + r) * K + k0 + (cb >> 1));
    }
    __syncthreads();
    short8 af[4], bfr[4];
#pragma unroll
    for (int s2 = 0; s2 < 4; ++s2) {
      int ra = wr * 64 + s2 * 16 + l15;
      int rb = wc * 64 + s2 * 16 + l15;
      af[s2]  = *(const short8*)((char*)lA + ra * 64 + ((lg * 16) ^ ((ra & 3) << 4)));
      bfr[s2] = *(const short8*)((char*)lB + rb * 64 + ((lg * 16) ^ ((rb & 3) << 4)));
    }
#pragma unroll
    for (int i = 0; i < 4; ++i)
#pragma unroll
      for (int j = 0; j < 4; ++j)
        acc[i][j] = MFMA16(af[i], bfr[j], acc[i][j]);
    __syncthreads();
  }

#pragma unroll
  for (int i = 0; i < 4; ++i)
#pragma unroll
    for (int j = 0; j < 4; ++j) {
      int row0 = m0 + wr * 64 + i * 16 + lg * 4;
      int col  = n0 + wc * 64 + j * 16 + l15;
      float bb = bias[col];
#pragma unroll
      for (int r = 0; r < 4; ++r) {
        float vv = acc[i][j][r] + bb;
        int row = row0 + r;
        if (gmode == 0) {
          ((unsigned short*)out0)[(size_t)row * N + col] = f2bf(vv);
        } else if (gmode == 1) {
          ((float*)out0)[(size_t)row * N + col] = vv;
        } else if (gmode == 2) {
          int b = row / 4000, l = row - b * 4000;
          int jj = l / 5, w = l - jj * 5;
          int sec = col >> 8, hh = (col >> 6) & 3, d = col & 63;
          unsigned short* dst = (sec == 0) ? (unsigned short*)out0
                               : (sec == 1) ? (unsigned short*)out1 : (unsigned short*)out2;
          dst[(((size_t)(b * 5 + w) * 4 + hh) * 800 + jj) * 64 + d] = f2bf(vv);
        } else {
          int b = row / 800, jj = row - b * 800;
          int hh = (col >> 6) & 3, d = col & 63;
          unsigned short* dst = (col < 256) ? (unsigned short*)out0 : (unsigned short*)out1;
          dst[(((size_t)b * 4 + hh) * 800 + jj) * 64 + d] = f2bf(vv);
        }
      }
    }
}

// ---------- flash attention v2 ----------
// Swapped QK^T (S^T = K x Q): lane holds S[q=l15][toks ns*16+lg*4+r].
// PV swapped (O^T = V^T x P^T): lane holds O[q=l15][d = ns2*16+lg*4+r].
// KVBLK=64, all LDS tiles XOR-swizzled (byte ^= (row&7)<<4 within 128B rows).
// K gathered [seq][800][64]; V pre-transposed [seq][64][800].
__global__ __launch_bounds__(256) void flash_v2(const unsigned short* __restrict__ qsrc,
                                                const unsigned short* __restrict__ ksrc,
                                                const unsigned short* __restrict__ vsrc,
                                                unsigned short* __restrict__ cat,
                                                int mode) {
  __shared__ unsigned short lK[64 * 64];   // [tok][d] swizzled
  __shared__ unsigned short lV[64 * 64];   // [d][tok] swizzled
  __shared__ unsigned short lP[4][16 * 64]; // per-wave [q16][tok64] swizzled

  const int tid = threadIdx.x, lane = tid & 63, wv = tid >> 6;
  const int l15 = lane & 15, lg = lane >> 4;
  const int sidx = blockIdx.y, qt = blockIdx.x;
  const int nk = 800;

  const unsigned short* Kb = ksrc + (long)sidx * 800 * 64;
  const unsigned short* Vb = vsrc + (long)sidx * 64 * 800;
  const unsigned short* Qb;
  unsigned short* Ob;
  long qstr, ostr;
  int nq;
  if (mode == 0) {
    int b = sidx / 20, rem = sidx % 20, w = rem >> 2, h = rem & 3;
    Qb = qsrc + (long)sidx * 800 * 64; qstr = 64;
    Ob = cat + ((long)b * 4000 + w) * 512 + h * 64; ostr = 2560;
    nq = 800;
  } else {
    int b = sidx >> 2, h = sidx & 3;
    Qb = qsrc + (long)b * 4000 * 256 + h * 64; qstr = 256;
    Ob = cat + (long)b * 4000 * 512 + 256 + h * 64; ostr = 512;
    nq = 4000;
  }

  // Q as B-fragment: lane (l15,lg) holds Q[q=l15][d = lg*8..+7] (+32 for q1)
  int qrow = qt * 64 + wv * 16 + l15;
  int qrc = min(qrow, nq - 1);
  short8 q0 = *(const short8*)(Qb + (long)qrc * qstr + lg * 8);
  short8 q1 = *(const short8*)(Qb + (long)qrc * qstr + 32 + lg * 8);

  float m = NEGBIG, ls = 0.f;   // stats for q = l15 (replicated across lg)
  f32x4 oacc[4] = {};           // O^T: oacc[ns2][r] = O[q=l15][d=ns2*16+lg*4+r]

  const int NT = 13;            // ceil(800/64)
  for (int t = 0; t < NT; ++t) {
    // ---- stage K [64 tok][64 d] and V^T [64 d][64 tok], swizzled ----
#pragma unroll
    for (int p = 0; p < 2; ++p) {
      int o = (p * 256 + tid) * 16;
      int row = o >> 7, colb = o & 127;
      int so = (o & ~127) | (colb ^ ((row & 7) << 4));
      int srck = min(t * 64 + row, nk - 1);
      *(float4*)((char*)lK + so) = *(const float4*)(Kb + (long)srck * 64 + (colb >> 1));
      int srcv = min(t * 64 + (colb >> 1), nk - 8);
      *(float4*)((char*)lV + so) = *(const float4*)(Vb + (long)row * 800 + srcv);
    }
    __syncthreads();

    // ---- S^T = K x Q : st[ns][r] = S[q=l15][tok = ns*16+lg*4+r] ----
    f32x4 st[4];
#pragma unroll
    for (int ns = 0; ns < 4; ++ns) {
      int row = ns * 16 + l15;
      short8 k0 = *(const short8*)((char*)lK + row * 128 + ((lg * 16) ^ ((l15 & 7) << 4)));
      short8 k1 = *(const short8*)((char*)lK + row * 128 + ((64 + lg * 16) ^ ((l15 & 7) << 4)));
      f32x4 z = {};
      z = MFMA16(k0, q0, z);
      z = MFMA16(k1, q1, z);
      st[ns] = z;
    }

    // ---- online softmax (q = l15; row split across 4 lg groups) ----
    float pv[16];
    float pmax = NEGBIG;
    int tokbase = t * 64 + lg * 4;
#pragma unroll
    for (int ns = 0; ns < 4; ++ns)
#pragma unroll
      for (int r = 0; r < 4; ++r) {
        float v = st[ns][r] * 0.125f;
        v = (tokbase + ns * 16 + r < nk) ? v : NEGBIG;
        pv[ns * 4 + r] = v;
        pmax = fmaxf(pmax, v);
      }
    pmax = fmaxf(pmax, __shfl_xor(pmax, 16));
    pmax = fmaxf(pmax, __shfl_xor(pmax, 32));
    float mn = fmaxf(m, pmax);
    float sc = __expf(m - mn);
    m = mn;
    float lsl = 0.f;
#pragma unroll
    for (int i = 0; i < 16; ++i) { float e = __expf(pv[i] - mn); pv[i] = e; lsl += e; }
    ls = ls * sc + lsl;
#pragma unroll
    for (int n = 0; n < 4; ++n) oacc[n] *= sc;

    // ---- pack P -> lP (wave-private), b64 swizzled writes ----
#pragma unroll
    for (int ns = 0; ns < 4; ++ns) {
      uint2 val;
      val.x = cvtpk(pv[ns * 4 + 0], pv[ns * 4 + 1]);
      val.y = cvtpk(pv[ns * 4 + 2], pv[ns * 4 + 3]);
      *(uint2*)((char*)(&lP[wv][0]) + l15 * 128 + ((ns * 32 + lg * 8) ^ ((l15 & 7) << 4))) = val;
    }
    asm volatile("" ::: "memory");   // keep lP writes before PV reads (same-wave LDS is in-order)

    // ---- O^T += V^T x P^T ----
#pragma unroll
    for (int half = 0; half < 2; ++half) {
      short8 pf = *(const short8*)((char*)(&lP[wv][0]) + l15 * 128 +
                                   ((half * 64 + lg * 16) ^ ((l15 & 7) << 4)));
#pragma unroll
      for (int ns2 = 0; ns2 < 4; ++ns2) {
        int row = ns2 * 16 + l15;
        short8 vf = *(const short8*)((char*)lV + row * 128 +
                                     ((half * 64 + lg * 16) ^ ((l15 & 7) << 4)));
        oacc[ns2] = MFMA16(vf, pf, oacc[ns2]);
      }
    }
    __syncthreads();
  }

  // ---- finalize: row sum across lg groups, normalize ----
  ls += __shfl_xor(ls, 16);
  ls += __shfl_xor(ls, 32);
  float inv = 1.0f / ls;

  // ---- transpose O through LDS (reuse lK): tile [64 q][64 d] swizzled ----
  {
    int qrl = wv * 16 + l15;
#pragma unroll
    for (int ns2 = 0; ns2 < 4; ++ns2) {
      uint2 val;
      val.x = (unsigned)f2bf(oacc[ns2][0] * inv) | ((unsigned)f2bf(oacc[ns2][1] * inv) << 16);
      val.y = (unsigned)f2bf(oacc[ns2][2] * inv) | ((unsigned)f2bf(oacc[ns2][3] * inv) << 16);
      *(uint2*)((char*)lK + qrl * 128 + ((ns2 * 32 + lg * 8) ^ ((l15 & 7) << 4))) = val;
    }
  }
  __syncthreads();
#pragma unroll
  for (int p = 0; p < 2; ++p) {
    int o = (p * 256 + tid) * 16;
    int row = o >> 7, colb = o & 127;
    int qg = qt * 64 + row;
    if (qg < nq) {
      float4 v = *(const float4*)((char*)lK + (o & ~127) + (colb ^ ((row & 7) << 4)));
      *(float4*)(Ob + (long)qg * ostr + (colb >> 1)) = v;
    }
  }
}

// ---------- launch ----------
extern "C" void kernel_launch(void* const* d_in, const int* in_sizes, int n_in,
                              void* d_out, int out_size, void* d_ws, size_t ws_size,
                              hipStream_t stream) {
  const float* x      = (const float*)d_in[0];
  const float* gqkv_w = (const float*)d_in[1];
  const float* gqkv_b = (const float*)d_in[2];
  const float* pq_w   = (const float*)d_in[3];
  const float* pq_b   = (const float*)d_in[4];
  const float* pkv_w  = (const float*)d_in[5];
  const float* pkv_b  = (const float*)d_in[6];
  const float* conv_w = (const float*)d_in[7];
  const float* conv_b = (const float*)d_in[8];
  const float* ln_g   = (const float*)d_in[9];
  const float* ln_b   = (const float*)d_in[10];
  const float* proj_w = (const float*)d_in[11];
  const float* proj_b = (const float*)d_in[12];

  char* ws = (char*)d_ws;
  // layout (bytes). High-water 264,765,440 (same as round 1).
  unsigned short* xbf  = (unsigned short*)(ws + 0);           // 65,536,000 (aliased by cat)
  unsigned short* cat  = xbf;
  unsigned short* qg   = (unsigned short*)(ws + 65536000);    // 32,768,000 grid Q gathered
  unsigned short* kg   = (unsigned short*)(ws + 98304000);    // 32,768,000 grid K gathered
  unsigned short* vg   = (unsigned short*)(ws + 131072000);   // 32,768,000 grid V gathered
  unsigned short* qp   = (unsigned short*)(ws + 163840000);   // 32,768,000 pool Q
  unsigned short* pr   = (unsigned short*)(ws + 196608000);   // 13,107,200 pooled (dead -> vtg)
  float*          cvt  = (float*)        (ws + 209715200);    // 26,214,400 conv out (dead -> vtg)
  unsigned short* vtg  = (unsigned short*)(ws + 196608000);   // 32,768,000 grid V^T (alias pr+cvt)
  unsigned short* p2   = (unsigned short*)(ws + 235929600);   // 13,107,200 ln+gelu (dead -> vtp)
  unsigned short* vtp  = (unsigned short*)(ws + 235929600);   //  6,553,600 pool V^T (alias p2)
  unsigned short* kp   = (unsigned short*)(ws + 249036800);   //  6,553,600 pool K gathered
  unsigned short* vp   = (unsigned short*)(ws + 255590400);   //  6,553,600 pool V gathered
  unsigned short* wtg  = (unsigned short*)(ws + 262144000);
  unsigned short* wtq  = (unsigned short*)(ws + 262930432);
  unsigned short* wtkv = (unsigned short*)(ws + 263192576);
  unsigned short* wtc  = (unsigned short*)(ws + 263716864);
  unsigned short* wtp  = (unsigned short*)(ws + 264241152);

  // prep
  cast_f32_bf16<<<32000, 256, 0, stream>>>(x, xbf, 64000L * 512);
  wtrans<<<(512 * 768 + 255) / 256, 256, 0, stream>>>(gqkv_w, wtg, 512, 768);
  wtrans<<<(512 * 256 + 255) / 256, 256, 0, stream>>>(pq_w, wtq, 512, 256);
  wtrans<<<(512 * 512 + 255) / 256, 256, 0, stream>>>(pkv_w, wtkv, 512, 512);
  wtrans<<<(512 * 512 + 255) / 256, 256, 0, stream>>>(conv_w, wtc, 512, 512);
  wtrans<<<(512 * 512 + 255) / 256, 256, 0, stream>>>(proj_w, wtp, 512, 512);
  pool_mean<<<12800, 256, 0, stream>>>(xbf, pr);

  // pool branch
  gemm_bf16<<<dim3(4, 100), 256, 0, stream>>>(pr, wtc, conv_b, cvt, nullptr, nullptr,
                                              12800, 512, 512, 1);
  ln_gelu<<<12800, 256, 0, stream>>>(cvt, ln_g, ln_b, p2);
  gemm_bf16<<<dim3(4, 100), 256, 0, stream>>>(p2, wtkv, pkv_b, kp, vp, nullptr,
                                              12800, 512, 512, 3);

  // projections
  gemm_bf16<<<dim3(6, 500), 256, 0, stream>>>(xbf, wtg, gqkv_b, qg, kg, vg,
                                              64000, 768, 512, 2);
  gemm_bf16<<<dim3(2, 500), 256, 0, stream>>>(xbf, wtq, pq_b, qp, nullptr, nullptr,
                                              64000, 256, 512, 0);

  // V transposes (pr/cvt and p2 dead by now)
  vtrans<<<dim3(13, 320), 256, 0, stream>>>(vg, vtg);
  vtrans<<<dim3(13, 64), 256, 0, stream>>>(vp, vtp);

  // attentions -> cat (xbf dead after pq GEMM)
  flash_v2<<<dim3(13, 320), 256, 0, stream>>>(qg, kg, vtg, cat, 0);
  flash_v2<<<dim3(63, 64), 256, 0, stream>>>(qp, kp, vtp, cat, 1);

  // output projection (fp32 out)
  gemm_bf16<<<dim3(4, 500), 256, 0, stream>>>(cat, wtp, proj_b, d_out, nullptr, nullptr,
                                              64000, 512, 512, 1);
}